// Round 16
// baseline (742.888 us; speedup 1.0000x reference)
//
#include <hip/hip_runtime.h>
#include <stdint.h>

typedef __attribute__((ext_vector_type(8))) short    bh8;   // 8 x bf16 (4 VGPR)
typedef __attribute__((ext_vector_type(4))) float    fx4;   // MFMA acc
typedef __attribute__((ext_vector_type(4))) float    f4v;
typedef unsigned short u16;
typedef __attribute__((ext_vector_type(4))) unsigned short u16x4;

#define DEV static __device__ __forceinline__

DEV u16 f2bf(float f) {                       // RNE fp32 -> bf16
  unsigned u = __float_as_uint(f);
  u += 0x7FFFu + ((u >> 16) & 1u);
  return (u16)(u >> 16);
}
DEV float bf2f(u16 s) { return __uint_as_float(((unsigned)s) << 16); }
DEV float softplus_f(float x) { return fmaxf(x, 0.f) + log1pf(expf(-fabsf(x))); }

DEV void gload_lds16(const u16* g, u16* l) {  // 16B/lane async global->LDS
  __builtin_amdgcn_global_load_lds(
      (const __attribute__((address_space(1))) unsigned int*)g,
      (__attribute__((address_space(3))) unsigned int*)l, 16, 0, 0);
}
DEV void stage2(const u16* s, u16* d) {       // one 128-row half-tile piece
  gload_lds16(s, d);
  gload_lds16(s + 131072, d + 4096);          // +64 rows (ld = 2048)
}

// ---------------- merged fp32 -> bf16 convert (1 launch for all 5) --------
__global__ __launch_bounds__(256) void k_cvt_all(
    const float* __restrict__ q, const float* __restrict__ k,
    const float* __restrict__ wq, const float* __restrict__ wk,
    const float* __restrict__ wv, u16* __restrict__ dst) {
  const int N4 = 19922944;
  int i = blockIdx.x * 256 + threadIdx.x;
  int stride = gridDim.x * 256;
  for (; i < N4; i += stride) {
    const float* src; int off;
    if (i < 8388608)        { src = q;  off = i; }
    else if (i < 16777216)  { src = k;  off = i - 8388608; }
    else if (i < 17825792)  { src = wq; off = i - 16777216; }
    else if (i < 18874368)  { src = wk; off = i - 17825792; }
    else                    { src = wv; off = i - 18874368; }
    f4v v = ((const f4v*)src)[off];
    u16x4 o;
    o.x = f2bf(v.x); o.y = f2bf(v.y); o.z = f2bf(v.z); o.w = f2bf(v.w);
    ((u16x4*)dst)[i] = o;
  }
}

// -------------------- shared GEMM macros --------------------
#define MM(a, b, c) __builtin_amdgcn_mfma_f32_16x16x32_bf16(a, b, c, 0, 0, 0)
#define LD(BASE, RR, KS) \
  (*(const bh8*)&lsg[(BASE) + (RR) * 64 + ((((KS) * 32) + ko8) ^ swz)])

#define STE(AC, EL, JOFF) {                                                   \
  float v = AC.EL;                                                            \
  if (EPI >= 1) v = softplus_f(v);                                            \
  if (EPI == 2) { if (mask[gi0 + JOFF]) v = 0.f; }                            \
  C[(size_t)(gi0 + JOFF) * 2048 + gj] = f2bf(v);                              \
}

// ====== VARIANT A (A/B test, GEMM1 only): 8-phase, ONE barrier per phase ===
// 256x256, BK=64, 8 waves 2Mx4N, per-wave 128x64 out (4 quadrants 64x32).
// Phase = [reads(p)][stage][BARRIER][lgkm0][16 MFMA] — no trailing barrier,
// so a wave finishing MFMA(p) issues reads(p+1) while its SIMD-mate still
// MFMAs: cross-wave LDS-port/MFMA overlap (the piece all r3-r12 lacked).
// vmcnt(0) PRE-barrier at P4/P8 -> collective staged-data guarantee before
// first reads of the fresh buffer (P5/P1'). Stages only in P1-P2/P5-P6.
#define DECLA(G)                                                         \
  bh8 a##G##_00 = {}, a##G##_01 = {}, a##G##_10 = {}, a##G##_11 = {},    \
      a##G##_20 = {}, a##G##_21 = {}, a##G##_30 = {}, a##G##_31 = {};
#define DECLB(J)                                                         \
  bh8 b##J##_00 = {}, b##J##_01 = {}, b##J##_10 = {}, b##J##_11 = {};
#define DECLQ8(Q)                                                         \
  fx4 acc##Q##00 = {}, acc##Q##01 = {}, acc##Q##10 = {}, acc##Q##11 = {}, \
      acc##Q##20 = {}, acc##Q##21 = {}, acc##Q##30 = {}, acc##Q##31 = {};

#define RDA8(G, BASE, RO)                                                    \
  a##G##_00 = LD(BASE, arow + (RO),      0);                                 \
  a##G##_01 = LD(BASE, arow + (RO),      1);                                 \
  a##G##_10 = LD(BASE, arow + (RO) + 16, 0);                                 \
  a##G##_11 = LD(BASE, arow + (RO) + 16, 1);                                 \
  a##G##_20 = LD(BASE, arow + (RO) + 32, 0);                                 \
  a##G##_21 = LD(BASE, arow + (RO) + 32, 1);                                 \
  a##G##_30 = LD(BASE, arow + (RO) + 48, 0);                                 \
  a##G##_31 = LD(BASE, arow + (RO) + 48, 1);

#define RDB4(J, BASE, CO)                                                    \
  b##J##_00 = LD(BASE, brow + (CO),      0);                                 \
  b##J##_01 = LD(BASE, brow + (CO),      1);                                 \
  b##J##_10 = LD(BASE, brow + (CO) + 16, 0);                                 \
  b##J##_11 = LD(BASE, brow + (CO) + 16, 1);

#define MFQ(G, J, Q)                                                         \
  acc##Q##00 = MM(a##G##_00, b##J##_00, acc##Q##00);                         \
  acc##Q##01 = MM(a##G##_00, b##J##_10, acc##Q##01);                         \
  acc##Q##10 = MM(a##G##_10, b##J##_00, acc##Q##10);                         \
  acc##Q##11 = MM(a##G##_10, b##J##_10, acc##Q##11);                         \
  acc##Q##20 = MM(a##G##_20, b##J##_00, acc##Q##20);                         \
  acc##Q##21 = MM(a##G##_20, b##J##_10, acc##Q##21);                         \
  acc##Q##30 = MM(a##G##_30, b##J##_00, acc##Q##30);                         \
  acc##Q##31 = MM(a##G##_30, b##J##_10, acc##Q##31);                         \
  acc##Q##00 = MM(a##G##_01, b##J##_01, acc##Q##00);                         \
  acc##Q##01 = MM(a##G##_01, b##J##_11, acc##Q##01);                         \
  acc##Q##10 = MM(a##G##_11, b##J##_01, acc##Q##10);                         \
  acc##Q##11 = MM(a##G##_11, b##J##_11, acc##Q##11);                         \
  acc##Q##20 = MM(a##G##_21, b##J##_01, acc##Q##20);                         \
  acc##Q##21 = MM(a##G##_21, b##J##_11, acc##Q##21);                         \
  acc##Q##30 = MM(a##G##_31, b##J##_01, acc##Q##30);                         \
  acc##Q##31 = MM(a##G##_31, b##J##_11, acc##Q##31);

// single-barrier phase: PRE (optional vmcnt) + reads/stages, barrier, lgkm0,
// prioritized MFMA cluster. NO trailing barrier.
#define PH8(MFMAS, PRE, ...) {                  \
  PRE                                           \
  __VA_ARGS__                                   \
  __builtin_amdgcn_s_barrier();                 \
  asm volatile("s_waitcnt lgkmcnt(0)");         \
  __builtin_amdgcn_s_setprio(1);                \
  MFMAS                                         \
  __builtin_amdgcn_s_setprio(0);                \
}
#define VM0 asm volatile("s_waitcnt vmcnt(0)");

#define STF(AC, MI, NI, RO, CO) {                                            \
  int gi0 = bm0 + wr * 128 + (RO) + (MI) * 16 + (lane >> 4) * 4;             \
  int gj  = bn0 + wc * 64 + (CO) + (NI) * 16 + l15;                          \
  STE(AC, x, 0) STE(AC, y, 1) STE(AC, z, 2) STE(AC, w, 3)                    \
}
#define EPQ8(Q, RO, CO)                                                      \
  STF(acc##Q##00, 0, 0, RO, CO) STF(acc##Q##01, 0, 1, RO, CO)                \
  STF(acc##Q##10, 1, 0, RO, CO) STF(acc##Q##11, 1, 1, RO, CO)                \
  STF(acc##Q##20, 2, 0, RO, CO) STF(acc##Q##21, 2, 1, RO, CO)                \
  STF(acc##Q##30, 3, 0, RO, CO) STF(acc##Q##31, 3, 1, RO, CO)

template <int EPI>
__global__ __launch_bounds__(512, 2) void k_gemm8p(
    const u16* __restrict__ A, const u16* __restrict__ B, u16* __restrict__ C,
    const int* __restrict__ mask) {
  extern __shared__ u16 lsg[];                 // 128 KiB dynamic
  int tid = threadIdx.x, lane = tid & 63, wid = tid >> 6;
  int xcd = blockIdx.x & 7, i = blockIdx.x >> 3;
  int bm0 = (xcd * 8 + (i & 7)) << 8;          // XCD-exclusive M-panels
  int bn0 = (i >> 3) << 8;
  int wr = wid >> 2, wc = wid & 3;             // 2M x 4N waves
  int l15 = lane & 15, ko8 = (lane >> 4) * 8;
  int swz = (l15 & 7) << 3;
  int arow = l15;                              // row within this wave's A half
  int brow = (wc & 1) * 64 + l15;              // row within this wave's B half
  int abw0 = wr * 8192, abw1 = 32768 + wr * 8192;
  int bbw0 = 16384 + (wc >> 1) * 8192, bbw1 = 49152 + (wc >> 1) * 8192;
  int lr = lane >> 3, cg = (lane & 7) ^ lr;
  const u16* srcA = A + (size_t)(bm0 + wid * 8 + lr) * 2048 + cg * 8;
  const u16* srcB = B + (size_t)(bn0 + wid * 8 + lr) * 2048 + cg * 8;
  u16* lsu = lsg + wid * 512;

  DECLQ8(0) DECLQ8(1) DECLQ8(2) DECLQ8(3)
  DECLA(L) DECLA(H) DECLB(0) DECLB(1)

  // prologue: buf0 <- tile0
  stage2(srcA,          lsu + 0);
  stage2(srcA + 262144, lsu + 8192);
  stage2(srcB,          lsu + 16384);
  stage2(srcB + 262144, lsu + 24576);
  asm volatile("s_waitcnt vmcnt(0)");
  __builtin_amdgcn_s_barrier();

  for (int it = 0; it < 16; it++) {
    const u16* sA1 = srcA + (2 * it + 1) * 64;
    const u16* sB1 = srcB + (2 * it + 1) * 64;
    int t2 = (2 * it + 2) & 31;                // wrapped (last-iter dup, unread)
    const u16* sA2 = srcA + t2 * 64;
    const u16* sB2 = srcB + t2 * 64;
    // K-tile 2it (buf0); stages fill buf1 <- tile 2it+1 in P1-P2
    PH8(MFQ(L, 0, 0), ,
        RDA8(L, abw0, 0) RDB4(0, bbw0, 0)
        stage2(sA1, lsu + 32768); stage2(sA1 + 262144, lsu + 40960);)
    PH8(MFQ(L, 1, 1), ,
        RDB4(1, bbw0, 32)
        stage2(sB1, lsu + 49152); stage2(sB1 + 262144, lsu + 57344);)
    PH8(MFQ(H, 0, 2), , RDA8(H, abw0, 64))
    PH8(MFQ(H, 1, 3), VM0, )                   // collective: buf1 landed
    // K-tile 2it+1 (buf1); stages fill buf0 <- tile 2it+2 in P5-P6
    PH8(MFQ(L, 0, 0), ,
        RDA8(L, abw1, 0) RDB4(0, bbw1, 0)
        stage2(sA2, lsu + 0); stage2(sA2 + 262144, lsu + 8192);)
    PH8(MFQ(L, 1, 1), ,
        RDB4(1, bbw1, 32)
        stage2(sB2, lsu + 16384); stage2(sB2 + 262144, lsu + 24576);)
    PH8(MFQ(H, 0, 2), , RDA8(H, abw1, 64))
    PH8(MFQ(H, 1, 3), VM0, )                   // collective: buf0 landed
  }

  EPQ8(0, 0, 0) EPQ8(1, 0, 32) EPQ8(2, 64, 0) EPQ8(3, 64, 32)
}

// ====== baseline r12 GEMM (GEMMs 2-3): single region per K-tile, 215us =====
#define DECLQ(Q)                                                          \
  fx4 acc##Q##00 = {}, acc##Q##01 = {}, acc##Q##10 = {}, acc##Q##11 = {}, \
      acc##Q##20 = {}, acc##Q##21 = {}, acc##Q##30 = {}, acc##Q##31 = {}

#define DECLFRAGS                                                         \
  bh8 a_00 = {}, a_01 = {}, a_10 = {}, a_11 = {},                         \
      a_20 = {}, a_21 = {}, a_30 = {}, a_31 = {};                         \
  bh8 b0_00 = {}, b0_01 = {}, b0_10 = {}, b0_11 = {};                     \
  bh8 b1_00 = {}, b1_01 = {}, b1_10 = {}, b1_11 = {};

#define LDA4(AB, KS)                                                     \
  a_0##KS = LD(AB, arow0,      KS); a_1##KS = LD(AB, arow0 + 16, KS);    \
  a_2##KS = LD(AB, arow0 + 32, KS); a_3##KS = LD(AB, arow0 + 48, KS);

#define LDB2(BN, BB, KS)                                                 \
  b##BN##_0##KS = LD(BB, brow0,      KS);                                \
  b##BN##_1##KS = LD(BB, brow0 + 16, KS);

#define MFMA8(Q, BN, KS)                                                 \
  acc##Q##00 = MM(a_0##KS, b##BN##_0##KS, acc##Q##00);                   \
  acc##Q##01 = MM(a_0##KS, b##BN##_1##KS, acc##Q##01);                   \
  acc##Q##10 = MM(a_1##KS, b##BN##_0##KS, acc##Q##10);                   \
  acc##Q##11 = MM(a_1##KS, b##BN##_1##KS, acc##Q##11);                   \
  acc##Q##20 = MM(a_2##KS, b##BN##_0##KS, acc##Q##20);                   \
  acc##Q##21 = MM(a_2##KS, b##BN##_1##KS, acc##Q##21);                   \
  acc##Q##30 = MM(a_3##KS, b##BN##_0##KS, acc##Q##30);                   \
  acc##Q##31 = MM(a_3##KS, b##BN##_1##KS, acc##Q##31);

#define KREGION(ABASE, BBASE, DA, DB, SA, SB) {                          \
  stage2(SA,            lsu + (DA));                                     \
  stage2((SA) + 262144, lsu + (DA) + 8192);                              \
  stage2(SB,            lsu + (DB));                                     \
  stage2((SB) + 262144, lsu + (DB) + 8192);                              \
  LDA4(ABASE, 0) LDA4(ABASE, 1)                                          \
  LDB2(0, BBASE, 0) LDB2(0, BBASE, 1)                                    \
  LDB2(1, (BBASE) + 8192, 0) LDB2(1, (BBASE) + 8192, 1)                  \
  __builtin_amdgcn_s_setprio(1);                                         \
  MFMA8(0, 0, 0) MFMA8(0, 0, 1) MFMA8(1, 1, 0) MFMA8(1, 1, 1)            \
  LDA4((ABASE) + 8192, 0) LDA4((ABASE) + 8192, 1)                        \
  MFMA8(2, 0, 0) MFMA8(2, 0, 1) MFMA8(3, 1, 0) MFMA8(3, 1, 1)            \
  __builtin_amdgcn_s_setprio(0);                                         \
  asm volatile("s_waitcnt vmcnt(0)");                                    \
  __builtin_amdgcn_s_barrier();                                          \
}

#define ST1(AC, QR, QC, MI, NI) {                                             \
  int gi0 = bm0 + (QR) * 128 + wr * 64 + (MI) * 16 + (lane >> 4) * 4;         \
  int gj  = bn0 + (QC) * 128 + wc * 32 + (NI) * 16 + l15;                     \
  STE(AC, x, 0) STE(AC, y, 1) STE(AC, z, 2) STE(AC, w, 3)                     \
}
#define EPIQ(Q, QR, QC)                                                       \
  ST1(acc##Q##00, QR, QC, 0, 0) ST1(acc##Q##01, QR, QC, 0, 1)                 \
  ST1(acc##Q##10, QR, QC, 1, 0) ST1(acc##Q##11, QR, QC, 1, 1)                 \
  ST1(acc##Q##20, QR, QC, 2, 0) ST1(acc##Q##21, QR, QC, 2, 1)                 \
  ST1(acc##Q##30, QR, QC, 3, 0) ST1(acc##Q##31, QR, QC, 3, 1)

template <int EPI>   // 0 plain, 1 softplus, 2 softplus + row-mask zero
__global__ __launch_bounds__(512, 2) void k_gemm256(
    const u16* __restrict__ A, const u16* __restrict__ B, u16* __restrict__ C,
    const int* __restrict__ mask) {
  extern __shared__ u16 lsg[];                 // 128 KiB dynamic
  int tid = threadIdx.x, lane = tid & 63, wid = tid >> 6;
  int xcd = blockIdx.x & 7, i = blockIdx.x >> 3;
  int bm0 = (xcd * 8 + (i & 7)) << 8;
  int bn0 = (i >> 3) << 8;
  int wr = wid >> 2, wc = wid & 3;
  int l15 = lane & 15, ko8 = (lane >> 4) * 8;
  int swz = (l15 & 7) << 3;
  int arow0 = wr * 64 + l15, brow0 = wc * 32 + l15;
  int lr = lane >> 3, cg = (lane & 7) ^ lr;
  const u16* srcA = A + (size_t)(bm0 + wid * 8 + lr) * 2048 + cg * 8;
  const u16* srcB = B + (size_t)(bn0 + wid * 8 + lr) * 2048 + cg * 8;
  u16* lsu = lsg + wid * 512;

  DECLQ(0); DECLQ(1); DECLQ(2); DECLQ(3);
  DECLFRAGS

  stage2(srcA,          lsu + 0);
  stage2(srcA + 262144, lsu + 8192);
  stage2(srcB,          lsu + 16384);
  stage2(srcB + 262144, lsu + 24576);
  asm volatile("s_waitcnt vmcnt(0)");
  __builtin_amdgcn_s_barrier();

  for (int it = 0; it < 16; it++) {
    const u16* sA1 = srcA + (2 * it + 1) * 64;
    const u16* sB1 = srcB + (2 * it + 1) * 64;
    int t2 = (2 * it + 2) & 31;
    const u16* sA2 = srcA + t2 * 64;
    const u16* sB2 = srcB + t2 * 64;
    KREGION(0,     16384, 32768, 49152, sA1, sB1)
    KREGION(32768, 49152, 0,     16384, sA2, sB2)
  }

  EPIQ(0, 0, 0)
  EPIQ(1, 0, 1)
  EPIQ(2, 1, 0)
  EPIQ(3, 1, 1)
}

// ------- split-K kv (+ s column-sums) -------
__global__ __launch_bounds__(256, 2) void k_kv2(const u16* __restrict__ pk,
                                                const u16* __restrict__ v,
                                                float* __restrict__ part,
                                                float* __restrict__ spart) {
  int nh = blockIdx.x >> 3, slab = blockIdx.x & 7;
  int n = nh >> 4, h = nh & 15;
  __shared__ u16 lsA[128 * 32];
  __shared__ u16 lsB[128 * 32];
  __shared__ float redS[32][128];
  int tid = threadIdx.x, lane = tid & 63, wid = tid >> 6;
  int wr = wid >> 1, wc = wid & 1;
  int kk = tid >> 3;
  int dg = (tid & 7) * 16;
  size_t rowbase = ((size_t)(n * 4096 + slab * 512) + kk) * 2048 + h * 128 + dg;
  int r = lane & 15, ko = (lane >> 4) * 8;
  fx4 acc[4][4] = {};
  float sA[16];
#pragma unroll
  for (int i = 0; i < 16; i++) sA[i] = 0.f;
  for (int k0 = 0; k0 < 512; k0 += 32) {
    __syncthreads();
    bh8 a0 = *(const bh8*)(pk + rowbase + (size_t)k0 * 2048);
    bh8 a1 = *(const bh8*)(pk + rowbase + (size_t)k0 * 2048 + 8);
    bh8 b0 = *(const bh8*)(v + rowbase + (size_t)k0 * 2048);
    bh8 b1 = *(const bh8*)(v + rowbase + (size_t)k0 * 2048 + 8);
#pragma unroll
    for (int i = 0; i < 8; i++) {
      sA[i] += bf2f((u16)a0[i]);
      sA[8 + i] += bf2f((u16)a1[i]);
    }
#pragma unroll
    for (int i = 0; i < 8; i++) {
      lsA[(dg + i) * 32 + kk] = (u16)a0[i];
      lsA[(dg + 8 + i) * 32 + kk] = (u16)a1[i];
      lsB[(dg + i) * 32 + kk] = (u16)b0[i];
      lsB[(dg + 8 + i) * 32 + kk] = (u16)b1[i];
    }
    __syncthreads();
    bh8 af[4], bfr[4];
#pragma unroll
    for (int mi = 0; mi < 4; mi++)
      af[mi] = *(const bh8*)&lsA[(wr * 64 + mi * 16 + r) * 32 + ko];
#pragma unroll
    for (int ni = 0; ni < 4; ni++)
      bfr[ni] = *(const bh8*)&lsB[(wc * 64 + ni * 16 + r) * 32 + ko];
#pragma unroll
    for (int mi = 0; mi < 4; mi++)
#pragma unroll
      for (int ni = 0; ni < 4; ni++)
        acc[mi][ni] = __builtin_amdgcn_mfma_f32_16x16x32_bf16(af[mi], bfr[ni],
                                                              acc[mi][ni], 0, 0, 0);
  }
#pragma unroll
  for (int mi = 0; mi < 4; mi++)
#pragma unroll
    for (int ni = 0; ni < 4; ni++)
#pragma unroll
      for (int j = 0; j < 4; j++) {
        int d = wr * 64 + mi * 16 + (lane >> 4) * 4 + j;
        int e = wc * 64 + ni * 16 + (lane & 15);
        part[(size_t)blockIdx.x * 16384 + e * 128 + d] = acc[mi][ni][j];
      }
#pragma unroll
  for (int i = 0; i < 16; i++) redS[kk][dg + i] = sA[i];
  __syncthreads();
  if (tid < 128) {
    float s = 0.f;
#pragma unroll
    for (int p = 0; p < 32; p++) s += redS[p][tid];
    spart[blockIdx.x * 128 + tid] = s;
  }
}

__global__ __launch_bounds__(256) void k_red(const float* __restrict__ part,
                                             const float* __restrict__ spart,
                                             u16* __restrict__ kvT,
                                             float* __restrict__ sb) {
  int nh = blockIdx.x, tid = threadIdx.x;
  for (int i = tid; i < 16384; i += 256) {
    float s = 0.f;
#pragma unroll
    for (int sl = 0; sl < 8; sl++) s += part[(size_t)(nh * 8 + sl) * 16384 + i];
    kvT[(size_t)nh * 16384 + i] = f2bf(s);
  }
  if (tid < 128) {
    float s = 0.f;
#pragma unroll
    for (int sl = 0; sl < 8; sl++) s += spart[(nh * 8 + sl) * 128 + tid];
    sb[nh * 128 + tid] = s;
  }
}

// ---------------- final: out = (pq @ kv) / (pq @ s), query-masked ----------
__global__ __launch_bounds__(256, 2) void k_att(
    const u16* __restrict__ pq, const u16* __restrict__ kvT,
    const float* __restrict__ s, const int* __restrict__ qmask,
    float* __restrict__ out) {
  int b = blockIdx.x;
  int lt = b & 31, h = (b >> 5) & 15, nb = b >> 9;
  int l0 = lt * 128;
  __shared__ u16 lsQ[128 * 128];
  __shared__ u16 lsKV[128 * 128];
  __shared__ float lsS[128];
  __shared__ float lsDen[128];
  int tid = threadIdx.x, lane = tid & 63, wid = tid >> 6;

  int row = tid >> 1, part = tid & 1;
  const u16* gq = pq + ((size_t)(nb * 4096 + l0 + row)) * 2048 + h * 128 + part * 64;
  const u16* gk = kvT + ((size_t)(nb * 16 + h) * 128 + row) * 128 + part * 64;
  int sw = (row & 7) << 3;
#pragma unroll
  for (int j = 0; j < 8; j++) {
    bh8 vq = *(const bh8*)(gq + j * 8);
    bh8 vk = *(const bh8*)(gk + j * 8);
    int ci = (part * 64 + j * 8) ^ sw;
    *(bh8*)&lsQ[row * 128 + ci] = vq;
    *(bh8*)&lsKV[row * 128 + ci] = vk;
  }
  if (tid < 128) lsS[tid] = s[(nb * 16 + h) * 128 + tid];
  __syncthreads();

  if (tid < 128) {
    int rr = tid, swr = (rr & 7) << 3;
    float dsum = 0.f;
    for (int dd = 0; dd < 128; dd++) {
      int d = (dd + rr) & 127;
      dsum += bf2f(lsQ[rr * 128 + (d ^ swr)]) * lsS[d];
    }
    lsDen[rr] = dsum;
  }
  __syncthreads();

  int wr = wid >> 1, wc = wid & 1;
  int r = lane & 15, ko = (lane >> 4) * 8;
  fx4 acc[4][4] = {};
#pragma unroll
  for (int ks = 0; ks < 4; ks++) {
    bh8 af[4], bfr[4];
#pragma unroll
    for (int mi = 0; mi < 4; mi++) {
      int rw = wr * 64 + mi * 16 + r;
      af[mi] = *(const bh8*)&lsQ[rw * 128 + ((ks * 32 + ko) ^ ((rw & 7) << 3))];
    }
#pragma unroll
    for (int ni = 0; ni < 4; ni++) {
      int rw = wc * 64 + ni * 16 + r;
      bfr[ni] = *(const bh8*)&lsKV[rw * 128 + ((ks * 32 + ko) ^ ((rw & 7) << 3))];
    }
#pragma unroll
    for (int mi = 0; mi < 4; mi++)
#pragma unroll
      for (int ni = 0; ni < 4; ni++)
        acc[mi][ni] = __builtin_amdgcn_mfma_f32_16x16x32_bf16(af[mi], bfr[ni],
                                                              acc[mi][ni], 0, 0, 0);
  }
#pragma unroll
  for (int mi = 0; mi < 4; mi++)
#pragma unroll
    for (int ni = 0; ni < 4; ni++)
#pragma unroll
      for (int j = 0; j < 4; j++) {
        int li = wr * 64 + mi * 16 + (lane >> 4) * 4 + j;
        int e = wc * 64 + ni * 16 + (lane & 15);
        int l = l0 + li;
        float v = qmask[nb * 4096 + l] ? 0.f : acc[mi][ni][j] / lsDen[li];
        out[((size_t)(nb * 4096 + l)) * 2048 + h * 128 + e] = v;
      }
}

// ---------------- launch ----------------
extern "C" void kernel_launch(void* const* d_in, const int* in_sizes, int n_in,
                              void* d_out, int out_size, void* d_ws, size_t ws_size,
                              hipStream_t stream) {
  const float* query = (const float*)d_in[0];
  const float* key   = (const float*)d_in[1];
  const float* Wq    = (const float*)d_in[2];
  const float* Wk    = (const float*)d_in[3];
  const float* Wv    = (const float*)d_in[4];
  const int* qmask   = (const int*)d_in[5];
  const int* kmask   = (const int*)d_in[6];
  float* out = (float*)d_out;
  char* ws = (char*)d_ws;

  u16* qb   = (u16*)(ws + 0);
  u16* kb   = (u16*)(ws + 67108864ull);
  u16* Wqb  = (u16*)(ws + 134217728ull);
  u16* Wkb  = (u16*)(ws + 142606336ull);
  u16* Wvb  = (u16*)(ws + 150994944ull);
  u16* pq   = (u16*)(ws + 159383552ull);
  u16* kvT  = (u16*)(ws + 226492416ull);
  float* sb = (float*)(ws + 228589568ull);
  float* kvpart = (float*)(ws + 0);            // aliases dead qb
  float* spart  = (float*)(ws + 33554432ull);
  u16* pk = (u16*)d_out;
  u16* vb = (u16*)d_out + 33554432ull;

  k_cvt_all<<<2048, 256, 0, stream>>>(query, key, Wq, Wk, Wv, qb);

  // A/B: GEMM1 uses the single-barrier 8-phase variant; GEMMs 2-3 baseline.
  k_gemm8p<1><<<512, 512, 131072, stream>>>(qb, Wqb, pq, nullptr);
  k_gemm256<2><<<512, 512, 131072, stream>>>(kb, Wkb, pk, kmask);
  k_gemm256<0><<<512, 512, 131072, stream>>>(kb, Wvb, vb, nullptr);

  k_kv2<<<512, 256, 0, stream>>>(pk, vb, kvpart, spart);
  k_red<<<64, 256, 0, stream>>>(kvpart, spart, kvT, sb);
  k_att<<<2048, 256, 0, stream>>>(pq, kvT, sb, qmask, out);
}

// Round 17
// 731.219 us; speedup vs baseline: 1.0160x; 1.0160x over previous
//
#include <hip/hip_runtime.h>
#include <stdint.h>

typedef __attribute__((ext_vector_type(8))) short    bh8;   // 8 x bf16 (4 VGPR)
typedef __attribute__((ext_vector_type(4))) float    fx4;   // MFMA acc
typedef __attribute__((ext_vector_type(4))) float    f4v;
typedef unsigned short u16;
typedef __attribute__((ext_vector_type(4))) unsigned short u16x4;

#define DEV static __device__ __forceinline__

DEV u16 f2bf(float f) {                       // RNE fp32 -> bf16
  unsigned u = __float_as_uint(f);
  u += 0x7FFFu + ((u >> 16) & 1u);
  return (u16)(u >> 16);
}
DEV float bf2f(u16 s) { return __uint_as_float(((unsigned)s) << 16); }
DEV float softplus_f(float x) { return fmaxf(x, 0.f) + log1pf(expf(-fabsf(x))); }

DEV void gload_lds16(const u16* g, u16* l) {  // 16B/lane async global->LDS
  __builtin_amdgcn_global_load_lds(
      (const __attribute__((address_space(1))) unsigned int*)g,
      (__attribute__((address_space(3))) unsigned int*)l, 16, 0, 0);
}
DEV void stage2(const u16* s, u16* d) {       // one 128-row half-tile piece
  gload_lds16(s, d);
  gload_lds16(s + 131072, d + 4096);          // +64 rows (ld = 2048)
}

// ---------------- merged fp32 -> bf16 convert (1 launch for all 5) --------
// dst = contiguous ws region qb|kb|Wqb|Wkb|Wvb (exactly 19922944 f4 groups).
__global__ __launch_bounds__(256) void k_cvt_all(
    const float* __restrict__ q, const float* __restrict__ k,
    const float* __restrict__ wq, const float* __restrict__ wk,
    const float* __restrict__ wv, u16* __restrict__ dst) {
  const int N4 = 19922944;
  int i = blockIdx.x * 256 + threadIdx.x;
  int stride = gridDim.x * 256;
  for (; i < N4; i += stride) {
    const float* src; int off;
    if (i < 8388608)        { src = q;  off = i; }
    else if (i < 16777216)  { src = k;  off = i - 8388608; }
    else if (i < 17825792)  { src = wq; off = i - 16777216; }
    else if (i < 18874368)  { src = wk; off = i - 17825792; }
    else                    { src = wv; off = i - 18874368; }
    f4v v = ((const f4v*)src)[off];
    u16x4 o;
    o.x = f2bf(v.x); o.y = f2bf(v.y); o.z = f2bf(v.z); o.w = f2bf(v.w);
    ((u16x4*)dst)[i] = o;
  }
}

// ====== 256x256 GEMM, single region per K-tile (session best: 215us) ======
// C[i,j] = sum_k A[i,k]*B[j,k]; M=16384, N=2048, K=2048 hardcoded.
// LDS (u16): buf0.A h0=0 h1=8192 buf0.B h0=16384 h1=24576; buf1 = +32768.
// Final note: 634 TF/GEMM (MfmaUtil 27%). Nine schedule variants (r3-r16)
// all landed 215-247us; probe decomposition (r10) shows MFMA/LDS-read/
// staging components stack serially in every hipcc formulation tried.
// The remaining ~2.4x to hand-tuned interleave requires asm-level
// scheduling. Verified mechanisms kept: XOR-swizzle (conflicts=0),
// linear-dest + inverse-swizzled-source staging (rule #21), XCD-chunked
// block map (FETCH 286->104 MB).

#define MM(a, b, c) __builtin_amdgcn_mfma_f32_16x16x32_bf16(a, b, c, 0, 0, 0)
#define LD(BASE, RR, KS) \
  (*(const bh8*)&lsg[(BASE) + (RR) * 64 + ((((KS) * 32) + ko8) ^ swz)])

#define DECLQ(Q)                                                          \
  fx4 acc##Q##00 = {}, acc##Q##01 = {}, acc##Q##10 = {}, acc##Q##11 = {}, \
      acc##Q##20 = {}, acc##Q##21 = {}, acc##Q##30 = {}, acc##Q##31 = {}

#define DECLFRAGS                                                         \
  bh8 a_00 = {}, a_01 = {}, a_10 = {}, a_11 = {},                         \
      a_20 = {}, a_21 = {}, a_30 = {}, a_31 = {};                         \
  bh8 b0_00 = {}, b0_01 = {}, b0_10 = {}, b0_11 = {};                     \
  bh8 b1_00 = {}, b1_01 = {}, b1_10 = {}, b1_11 = {};

#define LDA4(AB, KS)                                                     \
  a_0##KS = LD(AB, arow0,      KS); a_1##KS = LD(AB, arow0 + 16, KS);    \
  a_2##KS = LD(AB, arow0 + 32, KS); a_3##KS = LD(AB, arow0 + 48, KS);

#define LDB2(BN, BB, KS)                                                 \
  b##BN##_0##KS = LD(BB, brow0,      KS);                                \
  b##BN##_1##KS = LD(BB, brow0 + 16, KS);

#define MFMA8(Q, BN, KS)                                                 \
  acc##Q##00 = MM(a_0##KS, b##BN##_0##KS, acc##Q##00);                   \
  acc##Q##01 = MM(a_0##KS, b##BN##_1##KS, acc##Q##01);                   \
  acc##Q##10 = MM(a_1##KS, b##BN##_0##KS, acc##Q##10);                   \
  acc##Q##11 = MM(a_1##KS, b##BN##_1##KS, acc##Q##11);                   \
  acc##Q##20 = MM(a_2##KS, b##BN##_0##KS, acc##Q##20);                   \
  acc##Q##21 = MM(a_2##KS, b##BN##_1##KS, acc##Q##21);                   \
  acc##Q##30 = MM(a_3##KS, b##BN##_0##KS, acc##Q##30);                   \
  acc##Q##31 = MM(a_3##KS, b##BN##_1##KS, acc##Q##31);

// One K-tile: compute buf{ABASE,BBASE}, stage other buf {DA,DB} <- {SA,SB}.
#define KREGION(ABASE, BBASE, DA, DB, SA, SB) {                          \
  stage2(SA,            lsu + (DA));                                     \
  stage2((SA) + 262144, lsu + (DA) + 8192);                              \
  stage2(SB,            lsu + (DB));                                     \
  stage2((SB) + 262144, lsu + (DB) + 8192);                              \
  LDA4(ABASE, 0) LDA4(ABASE, 1)                                          \
  LDB2(0, BBASE, 0) LDB2(0, BBASE, 1)                                    \
  LDB2(1, (BBASE) + 8192, 0) LDB2(1, (BBASE) + 8192, 1)                  \
  __builtin_amdgcn_s_setprio(1);                                         \
  MFMA8(0, 0, 0) MFMA8(0, 0, 1) MFMA8(1, 1, 0) MFMA8(1, 1, 1)            \
  LDA4((ABASE) + 8192, 0) LDA4((ABASE) + 8192, 1)                        \
  MFMA8(2, 0, 0) MFMA8(2, 0, 1) MFMA8(3, 1, 0) MFMA8(3, 1, 1)            \
  __builtin_amdgcn_s_setprio(0);                                         \
  asm volatile("s_waitcnt vmcnt(0)");                                    \
  __builtin_amdgcn_s_barrier();                                          \
}

#define STE(AC, EL, JOFF) {                                                   \
  float v = AC.EL;                                                            \
  if (EPI >= 1) v = softplus_f(v);                                            \
  if (EPI == 2) { if (mask[gi0 + JOFF]) v = 0.f; }                            \
  C[(size_t)(gi0 + JOFF) * 2048 + gj] = f2bf(v);                              \
}
#define ST1(AC, QR, QC, MI, NI) {                                             \
  int gi0 = bm0 + (QR) * 128 + wr * 64 + (MI) * 16 + (lane >> 4) * 4;         \
  int gj  = bn0 + (QC) * 128 + wc * 32 + (NI) * 16 + l15;                     \
  STE(AC, x, 0) STE(AC, y, 1) STE(AC, z, 2) STE(AC, w, 3)                     \
}
#define EPIQ(Q, QR, QC)                                                       \
  ST1(acc##Q##00, QR, QC, 0, 0) ST1(acc##Q##01, QR, QC, 0, 1)                 \
  ST1(acc##Q##10, QR, QC, 1, 0) ST1(acc##Q##11, QR, QC, 1, 1)                 \
  ST1(acc##Q##20, QR, QC, 2, 0) ST1(acc##Q##21, QR, QC, 2, 1)                 \
  ST1(acc##Q##30, QR, QC, 3, 0) ST1(acc##Q##31, QR, QC, 3, 1)

template <int EPI>   // 0 plain, 1 softplus, 2 softplus + row-mask zero
__global__ __launch_bounds__(512, 2) void k_gemm256(
    const u16* __restrict__ A, const u16* __restrict__ B, u16* __restrict__ C,
    const int* __restrict__ mask) {
  extern __shared__ u16 lsg[];                 // 128 KiB dynamic
  int tid = threadIdx.x, lane = tid & 63, wid = tid >> 6;
  int xcd = blockIdx.x & 7, i = blockIdx.x >> 3;
  int bm0 = (xcd * 8 + (i & 7)) << 8;          // 64 M-tiles, XCD-exclusive
  int bn0 = (i >> 3) << 8;                     // 8 N-tiles
  int wr = wid >> 2, wc = wid & 3;
  int l15 = lane & 15, ko8 = (lane >> 4) * 8;
  int swz = (l15 & 7) << 3;
  int arow0 = wr * 64 + l15, brow0 = wc * 32 + l15;
  int lr = lane >> 3, cg = (lane & 7) ^ lr;    // inverse-swizzled source granule
  const u16* srcA = A + (size_t)(bm0 + wid * 8 + lr) * 2048 + cg * 8;
  const u16* srcB = B + (size_t)(bn0 + wid * 8 + lr) * 2048 + cg * 8;
  u16* lsu = lsg + wid * 512;                  // wave-uniform stage dest base

  DECLQ(0); DECLQ(1); DECLQ(2); DECLQ(3);
  DECLFRAGS

  // prologue: buf0 <- tile0 (all 4 halves); drain; barrier.
  stage2(srcA,          lsu + 0);              // b0.A h0
  stage2(srcA + 262144, lsu + 8192);           // b0.A h1
  stage2(srcB,          lsu + 16384);          // b0.B h0
  stage2(srcB + 262144, lsu + 24576);          // b0.B h1
  asm volatile("s_waitcnt vmcnt(0)");
  __builtin_amdgcn_s_barrier();

  for (int it = 0; it < 16; it++) {
    const u16* sA1 = srcA + (2 * it + 1) * 64;
    const u16* sB1 = srcB + (2 * it + 1) * 64;
    int t2 = (2 * it + 2) & 31;                // wrapped (last-iter dup, unread)
    const u16* sA2 = srcA + t2 * 64;
    const u16* sB2 = srcB + t2 * 64;
    // region 1: compute buf0, stage buf1 <- tile 2it+1
    KREGION(0,     16384, 32768, 49152, sA1, sB1)
    // region 2: compute buf1, stage buf0 <- tile 2it+2
    KREGION(32768, 49152, 0,     16384, sA2, sB2)
  }

  // epilogue: D row=(lane>>4)*4+reg, col=lane&15 (m89-verified)
  EPIQ(0, 0, 0)
  EPIQ(1, 0, 1)
  EPIQ(2, 1, 0)
  EPIQ(3, 1, 1)
}

// ------- split-K kv: part[bid][e*128+d] = sum_{k in slab} pk[k,d]*v[k,e] ----
// also computes s-partials (column sums of pk over the slab) from registers.
__global__ __launch_bounds__(256, 2) void k_kv2(const u16* __restrict__ pk,
                                                const u16* __restrict__ v,
                                                float* __restrict__ part,
                                                float* __restrict__ spart) {
  int nh = blockIdx.x >> 3, slab = blockIdx.x & 7;
  int n = nh >> 4, h = nh & 15;
  __shared__ u16 lsA[128 * 32];   // pk^T tile: [d][k]
  __shared__ u16 lsB[128 * 32];   // v^T tile:  [e][k]
  __shared__ float redS[32][128];
  int tid = threadIdx.x, lane = tid & 63, wid = tid >> 6;
  int wr = wid >> 1, wc = wid & 1;
  int kk = tid >> 3;              // 0..31 (k within 32-k slab)
  int dg = (tid & 7) * 16;        // 0..112 (16 cols per thread)
  size_t rowbase = ((size_t)(n * 4096 + slab * 512) + kk) * 2048 + h * 128 + dg;
  int r = lane & 15, ko = (lane >> 4) * 8;
  fx4 acc[4][4] = {};
  float sA[16];
#pragma unroll
  for (int i = 0; i < 16; i++) sA[i] = 0.f;
  for (int k0 = 0; k0 < 512; k0 += 32) {
    __syncthreads();
    bh8 a0 = *(const bh8*)(pk + rowbase + (size_t)k0 * 2048);
    bh8 a1 = *(const bh8*)(pk + rowbase + (size_t)k0 * 2048 + 8);
    bh8 b0 = *(const bh8*)(v + rowbase + (size_t)k0 * 2048);
    bh8 b1 = *(const bh8*)(v + rowbase + (size_t)k0 * 2048 + 8);
#pragma unroll
    for (int i = 0; i < 8; i++) {
      sA[i] += bf2f((u16)a0[i]);
      sA[8 + i] += bf2f((u16)a1[i]);
    }
#pragma unroll
    for (int i = 0; i < 8; i++) {
      lsA[(dg + i) * 32 + kk] = (u16)a0[i];
      lsA[(dg + 8 + i) * 32 + kk] = (u16)a1[i];
      lsB[(dg + i) * 32 + kk] = (u16)b0[i];
      lsB[(dg + 8 + i) * 32 + kk] = (u16)b1[i];
    }
    __syncthreads();
    bh8 af[4], bfr[4];
#pragma unroll
    for (int mi = 0; mi < 4; mi++)
      af[mi] = *(const bh8*)&lsA[(wr * 64 + mi * 16 + r) * 32 + ko];
#pragma unroll
    for (int ni = 0; ni < 4; ni++)
      bfr[ni] = *(const bh8*)&lsB[(wc * 64 + ni * 16 + r) * 32 + ko];
#pragma unroll
    for (int mi = 0; mi < 4; mi++)
#pragma unroll
      for (int ni = 0; ni < 4; ni++)
        acc[mi][ni] = __builtin_amdgcn_mfma_f32_16x16x32_bf16(af[mi], bfr[ni],
                                                              acc[mi][ni], 0, 0, 0);
  }
#pragma unroll
  for (int mi = 0; mi < 4; mi++)
#pragma unroll
    for (int ni = 0; ni < 4; ni++)
#pragma unroll
      for (int j = 0; j < 4; j++) {
        int d = wr * 64 + mi * 16 + (lane >> 4) * 4 + j;
        int e = wc * 64 + ni * 16 + (lane & 15);
        part[(size_t)blockIdx.x * 16384 + e * 128 + d] = acc[mi][ni][j];
      }
#pragma unroll
  for (int i = 0; i < 16; i++) redS[kk][dg + i] = sA[i];
  __syncthreads();
  if (tid < 128) {
    float s = 0.f;
#pragma unroll
    for (int p = 0; p < 32; p++) s += redS[p][tid];
    spart[blockIdx.x * 128 + tid] = s;
  }
}

// ------- reduce split-K partials -> kvT (bf16) and s (f32) -------
__global__ __launch_bounds__(256) void k_red(const float* __restrict__ part,
                                             const float* __restrict__ spart,
                                             u16* __restrict__ kvT,
                                             float* __restrict__ sb) {
  int nh = blockIdx.x, tid = threadIdx.x;
  for (int i = tid; i < 16384; i += 256) {
    float s = 0.f;
#pragma unroll
    for (int sl = 0; sl < 8; sl++) s += part[(size_t)(nh * 8 + sl) * 16384 + i];
    kvT[(size_t)nh * 16384 + i] = f2bf(s);
  }
  if (tid < 128) {
    float s = 0.f;
#pragma unroll
    for (int sl = 0; sl < 8; sl++) s += spart[(nh * 8 + sl) * 128 + tid];
    sb[nh * 128 + tid] = s;
  }
}

// ---------------- final: out = (pq @ kv) / (pq @ s), query-masked ----------
__global__ __launch_bounds__(256, 2) void k_att(
    const u16* __restrict__ pq, const u16* __restrict__ kvT,
    const float* __restrict__ s, const int* __restrict__ qmask,
    float* __restrict__ out) {
  int b = blockIdx.x;
  int lt = b & 31, h = (b >> 5) & 15, nb = b >> 9;
  int l0 = lt * 128;
  __shared__ u16 lsQ[128 * 128];
  __shared__ u16 lsKV[128 * 128];
  __shared__ float lsS[128];
  __shared__ float lsDen[128];
  int tid = threadIdx.x, lane = tid & 63, wid = tid >> 6;

  int row = tid >> 1, part = tid & 1;
  const u16* gq = pq + ((size_t)(nb * 4096 + l0 + row)) * 2048 + h * 128 + part * 64;
  const u16* gk = kvT + ((size_t)(nb * 16 + h) * 128 + row) * 128 + part * 64;
  int sw = (row & 7) << 3;
#pragma unroll
  for (int j = 0; j < 8; j++) {
    bh8 vq = *(const bh8*)(gq + j * 8);
    bh8 vk = *(const bh8*)(gk + j * 8);
    int ci = (part * 64 + j * 8) ^ sw;
    *(bh8*)&lsQ[row * 128 + ci] = vq;
    *(bh8*)&lsKV[row * 128 + ci] = vk;
  }
  if (tid < 128) lsS[tid] = s[(nb * 16 + h) * 128 + tid];
  __syncthreads();

  if (tid < 128) {
    int rr = tid, swr = (rr & 7) << 3;
    float dsum = 0.f;
    for (int dd = 0; dd < 128; dd++) {
      int d = (dd + rr) & 127;
      dsum += bf2f(lsQ[rr * 128 + (d ^ swr)]) * lsS[d];
    }
    lsDen[rr] = dsum;
  }
  __syncthreads();

  int wr = wid >> 1, wc = wid & 1;
  int r = lane & 15, ko = (lane >> 4) * 8;
  fx4 acc[4][4] = {};
#pragma unroll
  for (int ks = 0; ks < 4; ks++) {
    bh8 af[4], bfr[4];
#pragma unroll
    for (int mi = 0; mi < 4; mi++) {
      int rw = wr * 64 + mi * 16 + r;
      af[mi] = *(const bh8*)&lsQ[rw * 128 + ((ks * 32 + ko) ^ ((rw & 7) << 3))];
    }
#pragma unroll
    for (int ni = 0; ni < 4; ni++) {
      int rw = wc * 64 + ni * 16 + r;
      bfr[ni] = *(const bh8*)&lsKV[rw * 128 + ((ks * 32 + ko) ^ ((rw & 7) << 3))];
    }
#pragma unroll
    for (int mi = 0; mi < 4; mi++)
#pragma unroll
      for (int ni = 0; ni < 4; ni++)
        acc[mi][ni] = __builtin_amdgcn_mfma_f32_16x16x32_bf16(af[mi], bfr[ni],
                                                              acc[mi][ni], 0, 0, 0);
  }
#pragma unroll
  for (int mi = 0; mi < 4; mi++)
#pragma unroll
    for (int ni = 0; ni < 4; ni++)
#pragma unroll
      for (int j = 0; j < 4; j++) {
        int li = wr * 64 + mi * 16 + (lane >> 4) * 4 + j;
        int e = wc * 64 + ni * 16 + (lane & 15);
        int l = l0 + li;
        float v = qmask[nb * 4096 + l] ? 0.f : acc[mi][ni][j] / lsDen[li];
        out[((size_t)(nb * 4096 + l)) * 2048 + h * 128 + e] = v;
      }
}

// ---------------- launch ----------------
extern "C" void kernel_launch(void* const* d_in, const int* in_sizes, int n_in,
                              void* d_out, int out_size, void* d_ws, size_t ws_size,
                              hipStream_t stream) {
  const float* query = (const float*)d_in[0];
  const float* key   = (const float*)d_in[1];
  const float* Wq    = (const float*)d_in[2];
  const float* Wk    = (const float*)d_in[3];
  const float* Wv    = (const float*)d_in[4];
  const int* qmask   = (const int*)d_in[5];
  const int* kmask   = (const int*)d_in[6];
  float* out = (float*)d_out;
  char* ws = (char*)d_ws;

  u16* qb   = (u16*)(ws + 0);
  u16* kb   = (u16*)(ws + 67108864ull);
  u16* Wqb  = (u16*)(ws + 134217728ull);
  u16* Wkb  = (u16*)(ws + 142606336ull);
  u16* Wvb  = (u16*)(ws + 150994944ull);
  u16* pq   = (u16*)(ws + 159383552ull);
  u16* kvT  = (u16*)(ws + 226492416ull);
  float* sb = (float*)(ws + 228589568ull);
  float* kvpart = (float*)(ws + 0);            // aliases dead qb
  float* spart  = (float*)(ws + 33554432ull);
  u16* pk = (u16*)d_out;
  u16* vb = (u16*)d_out + 33554432ull;

  k_cvt_all<<<2048, 256, 0, stream>>>(query, key, Wq, Wk, Wv, qb);

  k_gemm256<1><<<512, 512, 131072, stream>>>(qb, Wqb, pq, nullptr);
  k_gemm256<2><<<512, 512, 131072, stream>>>(kb, Wkb, pk, kmask);
  k_gemm256<0><<<512, 512, 131072, stream>>>(kb, Wvb, vb, nullptr);

  k_kv2<<<512, 256, 0, stream>>>(pk, vb, kvpart, spart);
  k_red<<<64, 256, 0, stream>>>(kvpart, spart, kvT, sb);
  k_att<<<2048, 256, 0, stream>>>(pq, kvT, sb, qmask, out);
}

// Round 18
// 729.172 us; speedup vs baseline: 1.0188x; 1.0028x over previous
//
#include <hip/hip_runtime.h>
#include <stdint.h>

typedef __attribute__((ext_vector_type(8))) short    bh8;   // 8 x bf16 (4 VGPR)
typedef __attribute__((ext_vector_type(4))) float    fx4;   // MFMA acc
typedef __attribute__((ext_vector_type(4))) float    f4v;
typedef unsigned short u16;
typedef __attribute__((ext_vector_type(4))) unsigned short u16x4;

#define DEV static __device__ __forceinline__

DEV u16 f2bf(float f) {                       // RNE fp32 -> bf16
  unsigned u = __float_as_uint(f);
  u += 0x7FFFu + ((u >> 16) & 1u);
  return (u16)(u >> 16);
}
DEV float bf2f(u16 s) { return __uint_as_float(((unsigned)s) << 16); }
DEV float softplus_f(float x) { return fmaxf(x, 0.f) + log1pf(expf(-fabsf(x))); }

DEV void gload_lds16(const u16* g, u16* l) {  // 16B/lane async global->LDS
  __builtin_amdgcn_global_load_lds(
      (const __attribute__((address_space(1))) unsigned int*)g,
      (__attribute__((address_space(3))) unsigned int*)l, 16, 0, 0);
}
DEV void stage2(const u16* s, u16* d) {       // one 128-row half-tile piece
  gload_lds16(s, d);
  gload_lds16(s + 131072, d + 4096);          // +64 rows (ld = 2048)
}

// ---------------- merged fp32 -> bf16 convert (1 launch for all 5) --------
// dst = contiguous ws region qb|kb|Wqb|Wkb|Wvb (exactly 19922944 f4 groups).
__global__ __launch_bounds__(256) void k_cvt_all(
    const float* __restrict__ q, const float* __restrict__ k,
    const float* __restrict__ wq, const float* __restrict__ wk,
    const float* __restrict__ wv, u16* __restrict__ dst) {
  const int N4 = 19922944;
  int i = blockIdx.x * 256 + threadIdx.x;
  int stride = gridDim.x * 256;
  for (; i < N4; i += stride) {
    const float* src; int off;
    if (i < 8388608)        { src = q;  off = i; }
    else if (i < 16777216)  { src = k;  off = i - 8388608; }
    else if (i < 17825792)  { src = wq; off = i - 16777216; }
    else if (i < 18874368)  { src = wk; off = i - 17825792; }
    else                    { src = wv; off = i - 18874368; }
    f4v v = ((const f4v*)src)[off];
    u16x4 o;
    o.x = f2bf(v.x); o.y = f2bf(v.y); o.z = f2bf(v.z); o.w = f2bf(v.w);
    ((u16x4*)dst)[i] = o;
  }
}

// ====== 256x256 GEMM, single region per K-tile (session best: 215us) ======
// C[i,j] = sum_k A[i,k]*B[j,k]; M=16384, N=2048, K=2048 hardcoded.
// LDS (u16): buf0.A h0=0 h1=8192 buf0.B h0=16384 h1=24576; buf1 = +32768.
// 634 TF/GEMM (MfmaUtil 27%). Nine schedule variants (r3-r16) all landed
// 215-247us; probe decomposition (r10) shows MFMA/LDS-read/staging stack
// serially in every hipcc formulation tried; the remaining ~2.4x needs
// asm-level scheduling. Verified mechanisms kept: XOR-swizzle (conflicts=0),
// linear-dest + inverse-swizzled-source staging (rule #21), XCD-chunked
// block map (FETCH 286->104 MB).

#define MM(a, b, c) __builtin_amdgcn_mfma_f32_16x16x32_bf16(a, b, c, 0, 0, 0)
#define LD(BASE, RR, KS) \
  (*(const bh8*)&lsg[(BASE) + (RR) * 64 + ((((KS) * 32) + ko8) ^ swz)])

#define DECLQ(Q)                                                          \
  fx4 acc##Q##00 = {}, acc##Q##01 = {}, acc##Q##10 = {}, acc##Q##11 = {}, \
      acc##Q##20 = {}, acc##Q##21 = {}, acc##Q##30 = {}, acc##Q##31 = {}

#define DECLFRAGS                                                         \
  bh8 a_00 = {}, a_01 = {}, a_10 = {}, a_11 = {},                         \
      a_20 = {}, a_21 = {}, a_30 = {}, a_31 = {};                         \
  bh8 b0_00 = {}, b0_01 = {}, b0_10 = {}, b0_11 = {};                     \
  bh8 b1_00 = {}, b1_01 = {}, b1_10 = {}, b1_11 = {};

#define LDA4(AB, KS)                                                     \
  a_0##KS = LD(AB, arow0,      KS); a_1##KS = LD(AB, arow0 + 16, KS);    \
  a_2##KS = LD(AB, arow0 + 32, KS); a_3##KS = LD(AB, arow0 + 48, KS);

#define LDB2(BN, BB, KS)                                                 \
  b##BN##_0##KS = LD(BB, brow0,      KS);                                \
  b##BN##_1##KS = LD(BB, brow0 + 16, KS);

#define MFMA8(Q, BN, KS)                                                 \
  acc##Q##00 = MM(a_0##KS, b##BN##_0##KS, acc##Q##00);                   \
  acc##Q##01 = MM(a_0##KS, b##BN##_1##KS, acc##Q##01);                   \
  acc##Q##10 = MM(a_1##KS, b##BN##_0##KS, acc##Q##10);                   \
  acc##Q##11 = MM(a_1##KS, b##BN##_1##KS, acc##Q##11);                   \
  acc##Q##20 = MM(a_2##KS, b##BN##_0##KS, acc##Q##20);                   \
  acc##Q##21 = MM(a_2##KS, b##BN##_1##KS, acc##Q##21);                   \
  acc##Q##30 = MM(a_3##KS, b##BN##_0##KS, acc##Q##30);                   \
  acc##Q##31 = MM(a_3##KS, b##BN##_1##KS, acc##Q##31);

// One K-tile: compute buf{ABASE,BBASE}, stage other buf {DA,DB} <- {SA,SB}.
#define KREGION(ABASE, BBASE, DA, DB, SA, SB) {                          \
  stage2(SA,            lsu + (DA));                                     \
  stage2((SA) + 262144, lsu + (DA) + 8192);                              \
  stage2(SB,            lsu + (DB));                                     \
  stage2((SB) + 262144, lsu + (DB) + 8192);                              \
  LDA4(ABASE, 0) LDA4(ABASE, 1)                                          \
  LDB2(0, BBASE, 0) LDB2(0, BBASE, 1)                                    \
  LDB2(1, (BBASE) + 8192, 0) LDB2(1, (BBASE) + 8192, 1)                  \
  __builtin_amdgcn_s_setprio(1);                                         \
  MFMA8(0, 0, 0) MFMA8(0, 0, 1) MFMA8(1, 1, 0) MFMA8(1, 1, 1)            \
  LDA4((ABASE) + 8192, 0) LDA4((ABASE) + 8192, 1)                        \
  MFMA8(2, 0, 0) MFMA8(2, 0, 1) MFMA8(3, 1, 0) MFMA8(3, 1, 1)            \
  __builtin_amdgcn_s_setprio(0);                                         \
  asm volatile("s_waitcnt vmcnt(0)");                                    \
  __builtin_amdgcn_s_barrier();                                          \
}

#define STE(AC, EL, JOFF) {                                                   \
  float v = AC.EL;                                                            \
  if (EPI >= 1) v = softplus_f(v);                                            \
  if (EPI == 2) { if (mask[gi0 + JOFF]) v = 0.f; }                            \
  C[(size_t)(gi0 + JOFF) * 2048 + gj] = f2bf(v);                              \
}
#define ST1(AC, QR, QC, MI, NI) {                                             \
  int gi0 = bm0 + (QR) * 128 + wr * 64 + (MI) * 16 + (lane >> 4) * 4;         \
  int gj  = bn0 + (QC) * 128 + wc * 32 + (NI) * 16 + l15;                     \
  STE(AC, x, 0) STE(AC, y, 1) STE(AC, z, 2) STE(AC, w, 3)                     \
}
#define EPIQ(Q, QR, QC)                                                       \
  ST1(acc##Q##00, QR, QC, 0, 0) ST1(acc##Q##01, QR, QC, 0, 1)                 \
  ST1(acc##Q##10, QR, QC, 1, 0) ST1(acc##Q##11, QR, QC, 1, 1)                 \
  ST1(acc##Q##20, QR, QC, 2, 0) ST1(acc##Q##21, QR, QC, 2, 1)                 \
  ST1(acc##Q##30, QR, QC, 3, 0) ST1(acc##Q##31, QR, QC, 3, 1)

template <int EPI>   // 0 plain, 1 softplus, 2 softplus + row-mask zero
__global__ __launch_bounds__(512, 2) void k_gemm256(
    const u16* __restrict__ A, const u16* __restrict__ B, u16* __restrict__ C,
    const int* __restrict__ mask) {
  extern __shared__ u16 lsg[];                 // 128 KiB dynamic
  int tid = threadIdx.x, lane = tid & 63, wid = tid >> 6;
  int xcd = blockIdx.x & 7, i = blockIdx.x >> 3;
  int bm0 = (xcd * 8 + (i & 7)) << 8;          // 64 M-tiles, XCD-exclusive
  int bn0 = (i >> 3) << 8;                     // 8 N-tiles
  int wr = wid >> 2, wc = wid & 3;
  int l15 = lane & 15, ko8 = (lane >> 4) * 8;
  int swz = (l15 & 7) << 3;
  int arow0 = wr * 64 + l15, brow0 = wc * 32 + l15;
  int lr = lane >> 3, cg = (lane & 7) ^ lr;    // inverse-swizzled source granule
  const u16* srcA = A + (size_t)(bm0 + wid * 8 + lr) * 2048 + cg * 8;
  const u16* srcB = B + (size_t)(bn0 + wid * 8 + lr) * 2048 + cg * 8;
  u16* lsu = lsg + wid * 512;                  // wave-uniform stage dest base

  DECLQ(0); DECLQ(1); DECLQ(2); DECLQ(3);
  DECLFRAGS

  // prologue: buf0 <- tile0 (all 4 halves); drain; barrier.
  stage2(srcA,          lsu + 0);              // b0.A h0
  stage2(srcA + 262144, lsu + 8192);           // b0.A h1
  stage2(srcB,          lsu + 16384);          // b0.B h0
  stage2(srcB + 262144, lsu + 24576);          // b0.B h1
  asm volatile("s_waitcnt vmcnt(0)");
  __builtin_amdgcn_s_barrier();

  for (int it = 0; it < 16; it++) {
    const u16* sA1 = srcA + (2 * it + 1) * 64;
    const u16* sB1 = srcB + (2 * it + 1) * 64;
    int t2 = (2 * it + 2) & 31;                // wrapped (last-iter dup, unread)
    const u16* sA2 = srcA + t2 * 64;
    const u16* sB2 = srcB + t2 * 64;
    // region 1: compute buf0, stage buf1 <- tile 2it+1
    KREGION(0,     16384, 32768, 49152, sA1, sB1)
    // region 2: compute buf1, stage buf0 <- tile 2it+2
    KREGION(32768, 49152, 0,     16384, sA2, sB2)
  }

  // epilogue: D row=(lane>>4)*4+reg, col=lane&15 (m89-verified)
  EPIQ(0, 0, 0)
  EPIQ(1, 0, 1)
  EPIQ(2, 1, 0)
  EPIQ(3, 1, 1)
}

// ------- split-K kv: part[bid][e*128+d] = sum_{k in slab} pk[k,d]*v[k,e] ----
// also computes s-partials (column sums of pk over the slab) from registers.
__global__ __launch_bounds__(256, 2) void k_kv2(const u16* __restrict__ pk,
                                                const u16* __restrict__ v,
                                                float* __restrict__ part,
                                                float* __restrict__ spart) {
  int nh = blockIdx.x >> 3, slab = blockIdx.x & 7;
  int n = nh >> 4, h = nh & 15;
  __shared__ u16 lsA[128 * 32];   // pk^T tile: [d][k]
  __shared__ u16 lsB[128 * 32];   // v^T tile:  [e][k]
  __shared__ float redS[32][128];
  int tid = threadIdx.x, lane = tid & 63, wid = tid >> 6;
  int wr = wid >> 1, wc = wid & 1;
  int kk = tid >> 3;              // 0..31 (k within 32-k slab)
  int dg = (tid & 7) * 16;        // 0..112 (16 cols per thread)
  size_t rowbase = ((size_t)(n * 4096 + slab * 512) + kk) * 2048 + h * 128 + dg;
  int r = lane & 15, ko = (lane >> 4) * 8;
  fx4 acc[4][4] = {};
  float sA[16];
#pragma unroll
  for (int i = 0; i < 16; i++) sA[i] = 0.f;
  for (int k0 = 0; k0 < 512; k0 += 32) {
    __syncthreads();
    bh8 a0 = *(const bh8*)(pk + rowbase + (size_t)k0 * 2048);
    bh8 a1 = *(const bh8*)(pk + rowbase + (size_t)k0 * 2048 + 8);
    bh8 b0 = *(const bh8*)(v + rowbase + (size_t)k0 * 2048);
    bh8 b1 = *(const bh8*)(v + rowbase + (size_t)k0 * 2048 + 8);
#pragma unroll
    for (int i = 0; i < 8; i++) {
      sA[i] += bf2f((u16)a0[i]);
      sA[8 + i] += bf2f((u16)a1[i]);
    }
#pragma unroll
    for (int i = 0; i < 8; i++) {
      lsA[(dg + i) * 32 + kk] = (u16)a0[i];
      lsA[(dg + 8 + i) * 32 + kk] = (u16)a1[i];
      lsB[(dg + i) * 32 + kk] = (u16)b0[i];
      lsB[(dg + 8 + i) * 32 + kk] = (u16)b1[i];
    }
    __syncthreads();
    bh8 af[4], bfr[4];
#pragma unroll
    for (int mi = 0; mi < 4; mi++)
      af[mi] = *(const bh8*)&lsA[(wr * 64 + mi * 16 + r) * 32 + ko];
#pragma unroll
    for (int ni = 0; ni < 4; ni++)
      bfr[ni] = *(const bh8*)&lsB[(wc * 64 + ni * 16 + r) * 32 + ko];
#pragma unroll
    for (int mi = 0; mi < 4; mi++)
#pragma unroll
      for (int ni = 0; ni < 4; ni++)
        acc[mi][ni] = __builtin_amdgcn_mfma_f32_16x16x32_bf16(af[mi], bfr[ni],
                                                              acc[mi][ni], 0, 0, 0);
  }
#pragma unroll
  for (int mi = 0; mi < 4; mi++)
#pragma unroll
    for (int ni = 0; ni < 4; ni++)
#pragma unroll
      for (int j = 0; j < 4; j++) {
        int d = wr * 64 + mi * 16 + (lane >> 4) * 4 + j;
        int e = wc * 64 + ni * 16 + (lane & 15);
        part[(size_t)blockIdx.x * 16384 + e * 128 + d] = acc[mi][ni][j];
      }
#pragma unroll
  for (int i = 0; i < 16; i++) redS[kk][dg + i] = sA[i];
  __syncthreads();
  if (tid < 128) {
    float s = 0.f;
#pragma unroll
    for (int p = 0; p < 32; p++) s += redS[p][tid];
    spart[blockIdx.x * 128 + tid] = s;
  }
}

// ------- reduce split-K partials -> kvT (bf16) and s (f32), vectorized ----
__global__ __launch_bounds__(256) void k_red(const float* __restrict__ part,
                                             const float* __restrict__ spart,
                                             u16* __restrict__ kvT,
                                             float* __restrict__ sb) {
  int nh = blockIdx.x, tid = threadIdx.x;
  for (int i4 = tid; i4 < 4096; i4 += 256) {   // 4096 f4 groups = 16384 floats
    f4v s = {};
#pragma unroll
    for (int sl = 0; sl < 8; sl++) {
      f4v p = ((const f4v*)(part + (size_t)(nh * 8 + sl) * 16384))[i4];
      s.x += p.x; s.y += p.y; s.z += p.z; s.w += p.w;
    }
    u16x4 o;
    o.x = f2bf(s.x); o.y = f2bf(s.y); o.z = f2bf(s.z); o.w = f2bf(s.w);
    ((u16x4*)(kvT + (size_t)nh * 16384))[i4] = o;
  }
  if (tid < 128) {
    float s = 0.f;
#pragma unroll
    for (int sl = 0; sl < 8; sl++) s += spart[(nh * 8 + sl) * 128 + tid];
    sb[nh * 128 + tid] = s;
  }
}

// ---------------- final: out = (pq @ kv) / (pq @ s), query-masked ----------
__global__ __launch_bounds__(256, 2) void k_att(
    const u16* __restrict__ pq, const u16* __restrict__ kvT,
    const float* __restrict__ s, const int* __restrict__ qmask,
    float* __restrict__ out) {
  int b = blockIdx.x;
  int lt = b & 31, h = (b >> 5) & 15, nb = b >> 9;
  int l0 = lt * 128;
  __shared__ u16 lsQ[128 * 128];
  __shared__ u16 lsKV[128 * 128];
  __shared__ float lsS[128];
  __shared__ float lsDen[128];
  int tid = threadIdx.x, lane = tid & 63, wid = tid >> 6;

  int row = tid >> 1, part = tid & 1;
  const u16* gq = pq + ((size_t)(nb * 4096 + l0 + row)) * 2048 + h * 128 + part * 64;
  const u16* gk = kvT + ((size_t)(nb * 16 + h) * 128 + row) * 128 + part * 64;
  int sw = (row & 7) << 3;
#pragma unroll
  for (int j = 0; j < 8; j++) {
    bh8 vq = *(const bh8*)(gq + j * 8);
    bh8 vk = *(const bh8*)(gk + j * 8);
    int ci = (part * 64 + j * 8) ^ sw;
    *(bh8*)&lsQ[row * 128 + ci] = vq;
    *(bh8*)&lsKV[row * 128 + ci] = vk;
  }
  if (tid < 128) lsS[tid] = s[(nb * 16 + h) * 128 + tid];
  __syncthreads();

  // den per row: 2 threads/row (all 256 active), 64 elems each, pair-combine
  // via shfl_xor(1) (pairs are adjacent lanes, never straddle a wave).
  {
    int rr = tid >> 1, half = tid & 1, swr = (rr & 7) << 3;
    float dsum = 0.f;
    for (int dd = 0; dd < 64; dd++) {
      int d = half * 64 + ((dd + rr) & 63);
      dsum += bf2f(lsQ[rr * 128 + (d ^ swr)]) * lsS[d];
    }
    dsum += __shfl_xor(dsum, 1);
    if (half == 0) lsDen[rr] = dsum;
  }
  __syncthreads();

  int wr = wid >> 1, wc = wid & 1;
  int r = lane & 15, ko = (lane >> 4) * 8;
  fx4 acc[4][4] = {};
#pragma unroll
  for (int ks = 0; ks < 4; ks++) {
    bh8 af[4], bfr[4];
#pragma unroll
    for (int mi = 0; mi < 4; mi++) {
      int rw = wr * 64 + mi * 16 + r;
      af[mi] = *(const bh8*)&lsQ[rw * 128 + ((ks * 32 + ko) ^ ((rw & 7) << 3))];
    }
#pragma unroll
    for (int ni = 0; ni < 4; ni++) {
      int rw = wc * 64 + ni * 16 + r;
      bfr[ni] = *(const bh8*)&lsKV[rw * 128 + ((ks * 32 + ko) ^ ((rw & 7) << 3))];
    }
#pragma unroll
    for (int mi = 0; mi < 4; mi++)
#pragma unroll
      for (int ni = 0; ni < 4; ni++)
        acc[mi][ni] = __builtin_amdgcn_mfma_f32_16x16x32_bf16(af[mi], bfr[ni],
                                                              acc[mi][ni], 0, 0, 0);
  }
#pragma unroll
  for (int mi = 0; mi < 4; mi++)
#pragma unroll
    for (int ni = 0; ni < 4; ni++)
#pragma unroll
      for (int j = 0; j < 4; j++) {
        int li = wr * 64 + mi * 16 + (lane >> 4) * 4 + j;
        int e = wc * 64 + ni * 16 + (lane & 15);
        int l = l0 + li;
        float v = qmask[nb * 4096 + l] ? 0.f : acc[mi][ni][j] / lsDen[li];
        out[((size_t)(nb * 4096 + l)) * 2048 + h * 128 + e] = v;
      }
}

// ---------------- launch ----------------
extern "C" void kernel_launch(void* const* d_in, const int* in_sizes, int n_in,
                              void* d_out, int out_size, void* d_ws, size_t ws_size,
                              hipStream_t stream) {
  const float* query = (const float*)d_in[0];
  const float* key   = (const float*)d_in[1];
  const float* Wq    = (const float*)d_in[2];
  const float* Wk    = (const float*)d_in[3];
  const float* Wv    = (const float*)d_in[4];
  const int* qmask   = (const int*)d_in[5];
  const int* kmask   = (const int*)d_in[6];
  float* out = (float*)d_out;
  char* ws = (char*)d_ws;

  u16* qb   = (u16*)(ws + 0);
  u16* kb   = (u16*)(ws + 67108864ull);
  u16* Wqb  = (u16*)(ws + 134217728ull);
  u16* Wkb  = (u16*)(ws + 142606336ull);
  u16* Wvb  = (u16*)(ws + 150994944ull);
  u16* pq   = (u16*)(ws + 159383552ull);
  u16* kvT  = (u16*)(ws + 226492416ull);
  float* sb = (float*)(ws + 228589568ull);
  float* kvpart = (float*)(ws + 0);            // aliases dead qb
  float* spart  = (float*)(ws + 33554432ull);
  u16* pk = (u16*)d_out;
  u16* vb = (u16*)d_out + 33554432ull;

  k_cvt_all<<<2048, 256, 0, stream>>>(query, key, Wq, Wk, Wv, qb);

  k_gemm256<1><<<512, 512, 131072, stream>>>(qb, Wqb, pq, nullptr);
  k_gemm256<2><<<512, 512, 131072, stream>>>(kb, Wkb, pk, kmask);
  k_gemm256<0><<<512, 512, 131072, stream>>>(kb, Wvb, vb, nullptr);

  k_kv2<<<512, 256, 0, stream>>>(pk, vb, kvpart, spart);
  k_red<<<64, 256, 0, stream>>>(kvpart, spart, kvT, sb);
  k_att<<<2048, 256, 0, stream>>>(pq, kvT, sb, qmask, out);
}